// Round 2
// baseline (180.026 us; speedup 1.0000x reference)
//
#include <hip/hip_runtime.h>
#include <hip/hip_bf16.h>
#include <math.h>

typedef __bf16 bf16;
typedef __bf16 bf16x4 __attribute__((ext_vector_type(4)));
typedef __bf16 bf16x8 __attribute__((ext_vector_type(8)));
typedef float  f32x4  __attribute__((ext_vector_type(4)));

#define HD 512
#define NB 128
#define NS 512
#define MS (NB*NS)   // 65536

__device__ __forceinline__ float sigmoidf_(float x){ return 1.0f/(1.0f+expf(-x)); }

// ---------------- K0: convert W1 (512x512 fp32) -> bf16 ----------------
__global__ __launch_bounds__(256) void cvt_w1(const float* __restrict__ W1, bf16* __restrict__ W1bf){
    int t = blockIdx.x*256 + threadIdx.x;      // 65536 threads, 4 elems each
    f32x4 v = *(const f32x4*)&W1[(size_t)t*4];
    bf16x4 o;
    #pragma unroll
    for (int j=0;j<4;++j) o[j] = (bf16)v[j];
    *(bf16x4*)&W1bf[(size_t)t*4] = o;
}

// ---------------- K1/K2: small GEMM, 3-term bf16 split (fp32-grade) ----
// C[M x N] = A[M x K] * Bt[N x K]^T + rowbias.  K = Ksegs*512, segment s
// of A rows from A1/A2, Bt rows from B1/B2.  Tile 64x64, 256 threads.
__global__ __launch_bounds__(256) void gemm_split(
    const float* __restrict__ A1, const float* __restrict__ A2,
    const float* __restrict__ B1, const float* __restrict__ B2,
    const float* __restrict__ bias1, const float* __restrict__ bias2,
    float* __restrict__ C, int N, int Ksegs)
{
    __shared__ bf16 Ah[64][32], Al[64][32], Bh[64][32], Bl[64][32];
    int tid = threadIdx.x;
    int bm = blockIdx.x, bn = blockIdx.y;
    int w = tid>>6, l = tid&63;
    int wm = w>>1, wn = w&1;
    f32x4 acc[2][2] = {};
    int KT = Ksegs*512;
    for (int k0 = 0; k0 < KT; k0 += 32){
        const float* Ap = (k0 < 512) ? A1 : A2;
        const float* Bp = (k0 < 512) ? B1 : B2;
        int kk = k0 & 511;
        __syncthreads();
        #pragma unroll
        for (int q = 0; q < 2; ++q){
            int id  = q*256 + tid;            // 0..511
            int row = id >> 3, c4 = (id & 7)*4;
            f32x4 va = *(const f32x4*)&Ap[(size_t)(bm*64+row)*512 + kk + c4];
            f32x4 vb = *(const f32x4*)&Bp[(size_t)(bn*64+row)*512 + kk + c4];
            bf16x4 vah, val_, vbh, vbl;
            #pragma unroll
            for (int j=0;j<4;++j){
                bf16 ha = (bf16)va[j]; vah[j]=ha; val_[j]=(bf16)(va[j]-(float)ha);
                bf16 hb = (bf16)vb[j]; vbh[j]=hb; vbl[j]=(bf16)(vb[j]-(float)hb);
            }
            *(bf16x4*)&Ah[row][c4] = vah;  *(bf16x4*)&Al[row][c4] = val_;
            *(bf16x4*)&Bh[row][c4] = vbh;  *(bf16x4*)&Bl[row][c4] = vbl;
        }
        __syncthreads();
        int koff = (l>>4)*8;
        int ar = wm*32 + (l&15);
        int br = wn*32 + (l&15);
        bf16x8 ah[2], al[2], bh[2], bl[2];
        ah[0]=*(const bf16x8*)&Ah[ar][koff];    ah[1]=*(const bf16x8*)&Ah[ar+16][koff];
        al[0]=*(const bf16x8*)&Al[ar][koff];    al[1]=*(const bf16x8*)&Al[ar+16][koff];
        bh[0]=*(const bf16x8*)&Bh[br][koff];    bh[1]=*(const bf16x8*)&Bh[br+16][koff];
        bl[0]=*(const bf16x8*)&Bl[br][koff];    bl[1]=*(const bf16x8*)&Bl[br+16][koff];
        #pragma unroll
        for (int fm=0; fm<2; ++fm)
        #pragma unroll
        for (int fn=0; fn<2; ++fn){
            acc[fm][fn] = __builtin_amdgcn_mfma_f32_16x16x32_bf16(ah[fm], bh[fn], acc[fm][fn],0,0,0);
            acc[fm][fn] = __builtin_amdgcn_mfma_f32_16x16x32_bf16(ah[fm], bl[fn], acc[fm][fn],0,0,0);
            acc[fm][fn] = __builtin_amdgcn_mfma_f32_16x16x32_bf16(al[fm], bh[fn], acc[fm][fn],0,0,0);
        }
    }
    #pragma unroll
    for (int fm=0; fm<2; ++fm)
    #pragma unroll
    for (int fn=0; fn<2; ++fn){
        #pragma unroll
        for (int r=0; r<4; ++r){
            int m = bm*64 + wm*32 + fm*16 + ((l>>4)<<2) + r;
            int n = bn*64 + wn*32 + fn*16 + (l&15);
            float bias = 0.f;
            if (bias1) bias += bias1[m];
            if (bias2) bias += bias2[m];
            C[(size_t)m*N + n] = acc[fm][fn][r] + bias;
        }
    }
}

// ---------------- K1b: LSTM pointwise ----------------------------------
__global__ __launch_bounds__(256) void lstm_pointwise(
    const float* __restrict__ gates, const float* __restrict__ c_in,
    float* __restrict__ h_out, float* __restrict__ c_out)
{
    int t = blockIdx.x*256 + threadIdx.x;      // 65536 = b*512 + h
    int b = t >> 9, hh = t & 511;
    float gi = gates[(size_t)(0*512+hh)*128 + b];
    float gf = gates[(size_t)(1*512+hh)*128 + b];
    float gg = gates[(size_t)(2*512+hh)*128 + b];
    float go = gates[(size_t)(3*512+hh)*128 + b];
    float i = sigmoidf_(gi), f = sigmoidf_(gf), g = tanhf(gg), o = sigmoidf_(go);
    float cn = f*c_in[t] + i*g;
    float hn = o*tanhf(cn);
    h_out[t] = hn;  c_out[t] = cn;
}

// ---------------- K3: main fused GEMM + tanh*V reduce ------------------
// Block: 64 rows (one b), full N=512.  8 waves: wm=w>>1 (16 rows each), wn=w&1 (256 cols).
__global__ __launch_bounds__(512) void attn_main(
    const float* __restrict__ enc, const bf16* __restrict__ W1bf,
    const float* __restrict__ w2h, const float* __restrict__ Vv,
    float* __restrict__ a_out)
{
    __shared__ bf16 Asub[64][32];
    __shared__ bf16 Bsub[512][32];
    __shared__ float w2h_s[512];
    __shared__ float V_s[512];
    __shared__ float red[64][2];
    int tid = threadIdx.x;
    int m0 = blockIdx.x * 64;
    int bidx = blockIdx.x >> 3;
    w2h_s[tid] = w2h[(size_t)tid*128 + bidx];
    V_s[tid]   = Vv[tid];
    int w = tid>>6, l = tid&63;
    int wm = w>>1, wn = w&1;
    int koff = (l>>4)*8;
    int arow = wm*16 + (l&15);
    f32x4 acc[16] = {};
    for (int ki = 0; ki < 16; ++ki){
        int k0 = ki*32;
        __syncthreads();
        {   // stage A (fp32 -> bf16), 512 float4 = one per thread
            int row = tid>>3, c4 = (tid&7)*4;
            f32x4 v = *(const f32x4*)&enc[(size_t)(m0+row)*512 + k0 + c4];
            bf16x4 hv;
            #pragma unroll
            for (int j=0;j<4;++j) hv[j]=(bf16)v[j];
            *(bf16x4*)&Asub[row][c4] = hv;
        }
        #pragma unroll
        for (int q=0;q<4;++q){  // stage B (bf16 copy): 2048 x 16B
            int idx = q*512 + tid;
            int n = idx>>2, part = (idx&3)*8;
            bf16x8 v = *(const bf16x8*)&W1bf[(size_t)n*512 + k0 + part];
            *(bf16x8*)&Bsub[n][part] = v;
        }
        __syncthreads();
        bf16x8 af = *(const bf16x8*)&Asub[arow][koff];
        #pragma unroll
        for (int f=0; f<16; ++f){
            bf16x8 bfr = *(const bf16x8*)&Bsub[wn*256 + f*16 + (l&15)][koff];
            acc[f] = __builtin_amdgcn_mfma_f32_16x16x32_bf16(af, bfr, acc[f],0,0,0);
        }
    }
    // epilogue: asum[r] = sum_o tanh(C + w2h[o]) * V[o]
    float asum[4] = {0.f,0.f,0.f,0.f};
    #pragma unroll
    for (int f=0; f<16; ++f){
        int o = wn*256 + f*16 + (l&15);
        float wv = w2h_s[o], vv = V_s[o];
        #pragma unroll
        for (int r=0;r<4;++r){
            float t = tanhf(acc[f][r] + wv);
            asum[r] += t * vv;
        }
    }
    #pragma unroll
    for (int off=1; off<16; off<<=1){
        #pragma unroll
        for (int r=0;r<4;++r) asum[r] += __shfl_xor(asum[r], off, 64);
    }
    if ((l&15)==0){
        #pragma unroll
        for (int r=0;r<4;++r) red[wm*16 + (l>>4)*4 + r][wn] = asum[r];
    }
    __syncthreads();
    if (tid < 64){
        float a = red[tid][0] + red[tid][1];
        a_out[m0 + tid] = 10.0f * tanhf(a);
    }
}

// ---------------- K4: masked softmax over S=512 per row ----------------
__global__ __launch_bounds__(512) void softmax_k(
    const float* __restrict__ a10, const float* __restrict__ mask,
    float* __restrict__ out)
{
    int b = blockIdx.x, tid = threadIdx.x;
    __shared__ float sred[8];
    float v = a10[(size_t)b*512 + tid] + logf(mask[(size_t)b*512 + tid]);
    float m = v;
    #pragma unroll
    for (int off=1; off<64; off<<=1) m = fmaxf(m, __shfl_xor(m, off, 64));
    if ((tid&63)==0) sred[tid>>6] = m;
    __syncthreads();
    float mt = sred[0];
    #pragma unroll
    for (int i=1;i<8;++i) mt = fmaxf(mt, sred[i]);
    float e = expf(v - mt);
    float s = e;
    #pragma unroll
    for (int off=1; off<64; off<<=1) s += __shfl_xor(s, off, 64);
    __syncthreads();
    if ((tid&63)==0) sred[tid>>6] = s;
    __syncthreads();
    float st = 0.f;
    #pragma unroll
    for (int i=0;i<8;++i) st += sred[i];
    out[(size_t)b*512 + tid] = e / st;
}

extern "C" void kernel_launch(void* const* d_in, const int* in_sizes, int n_in,
                              void* d_out, int out_size, void* d_ws, size_t ws_size,
                              hipStream_t stream)
{
    const float* x    = (const float*)d_in[0];
    const float* h    = (const float*)d_in[1];
    const float* c    = (const float*)d_in[2];
    const float* enc  = (const float*)d_in[3];
    const float* mask = (const float*)d_in[4];
    const float* W1   = (const float*)d_in[5];
    const float* W2   = (const float*)d_in[6];
    const float* b2   = (const float*)d_in[7];
    const float* V    = (const float*)d_in[8];
    const float* Wih  = (const float*)d_in[9];
    const float* Whh  = (const float*)d_in[10];
    const float* bih  = (const float*)d_in[11];
    const float* bhh  = (const float*)d_in[12];

    float* out_policy = (float*)d_out;
    float* out_h = out_policy + MS;
    float* out_c = out_policy + 2*MS;

    float* ws_f  = (float*)d_ws;
    float* gates = ws_f;                 // 262144 f32
    float* w2h   = ws_f + 262144;        //  65536 f32  [o][b]
    float* a10   = ws_f + 327680;        //  65536 f32
    bf16*  W1bf  = (bf16*)(ws_f + 393216); // 262144 bf16

    cvt_w1<<<256, 256, 0, stream>>>(W1, W1bf);
    // gates[j][b], j = gate*512 + h
    gemm_split<<<dim3(32,2), 256, 0, stream>>>(Wih, Whh, x, h, bih, bhh, gates, 128, 2);
    lstm_pointwise<<<256, 256, 0, stream>>>(gates, c, out_h, out_c);
    // w2h[o][b]
    gemm_split<<<dim3(8,2), 256, 0, stream>>>(W2, nullptr, out_h, nullptr, b2, nullptr, w2h, 128, 1);
    attn_main<<<1024, 512, 0, stream>>>(enc, W1bf, w2h, V, a10);
    softmax_k<<<128, 512, 0, stream>>>(a10, mask, out_policy);
}

// Round 3
// 167.023 us; speedup vs baseline: 1.0778x; 1.0778x over previous
//
#include <hip/hip_runtime.h>
#include <hip/hip_bf16.h>
#include <math.h>

typedef __bf16 bf16;
typedef __bf16 bf16x4 __attribute__((ext_vector_type(4)));
typedef __bf16 bf16x8 __attribute__((ext_vector_type(8)));
typedef float  f32x4  __attribute__((ext_vector_type(4)));

#define HD 512
#define NB 128
#define NS 512
#define MS (NB*NS)   // 65536

__device__ __forceinline__ float sigmoidf_(float x){ return 1.0f/(1.0f+expf(-x)); }

// ---------------- K0: convert W1 (512x512 fp32) -> bf16 ----------------
__global__ __launch_bounds__(256) void cvt_w1(const float* __restrict__ W1, bf16* __restrict__ W1bf){
    int t = blockIdx.x*256 + threadIdx.x;
    f32x4 v = *(const f32x4*)&W1[(size_t)t*4];
    bf16x4 o;
    #pragma unroll
    for (int j=0;j<4;++j) o[j] = (bf16)v[j];
    *(bf16x4*)&W1bf[(size_t)t*4] = o;
}

// ---------------- K1/K2: small GEMM, 3-term bf16 split (fp32-grade) ----
__global__ __launch_bounds__(256) void gemm_split(
    const float* __restrict__ A1, const float* __restrict__ A2,
    const float* __restrict__ B1, const float* __restrict__ B2,
    const float* __restrict__ bias1, const float* __restrict__ bias2,
    float* __restrict__ C, int N, int Ksegs)
{
    __shared__ bf16 Ah[64][32], Al[64][32], Bh[64][32], Bl[64][32];
    int tid = threadIdx.x;
    int bm = blockIdx.x, bn = blockIdx.y;
    int w = tid>>6, l = tid&63;
    int wm = w>>1, wn = w&1;
    f32x4 acc[2][2] = {};
    int KT = Ksegs*512;
    for (int k0 = 0; k0 < KT; k0 += 32){
        const float* Ap = (k0 < 512) ? A1 : A2;
        const float* Bp = (k0 < 512) ? B1 : B2;
        int kk = k0 & 511;
        __syncthreads();
        #pragma unroll
        for (int q = 0; q < 2; ++q){
            int id  = q*256 + tid;
            int row = id >> 3, c4 = (id & 7)*4;
            f32x4 va = *(const f32x4*)&Ap[(size_t)(bm*64+row)*512 + kk + c4];
            f32x4 vb = *(const f32x4*)&Bp[(size_t)(bn*64+row)*512 + kk + c4];
            bf16x4 vah, val_, vbh, vbl;
            #pragma unroll
            for (int j=0;j<4;++j){
                bf16 ha = (bf16)va[j]; vah[j]=ha; val_[j]=(bf16)(va[j]-(float)ha);
                bf16 hb = (bf16)vb[j]; vbh[j]=hb; vbl[j]=(bf16)(vb[j]-(float)hb);
            }
            *(bf16x4*)&Ah[row][c4] = vah;  *(bf16x4*)&Al[row][c4] = val_;
            *(bf16x4*)&Bh[row][c4] = vbh;  *(bf16x4*)&Bl[row][c4] = vbl;
        }
        __syncthreads();
        int koff = (l>>4)*8;
        int ar = wm*32 + (l&15);
        int br = wn*32 + (l&15);
        bf16x8 ah[2], al[2], bh[2], bl[2];
        ah[0]=*(const bf16x8*)&Ah[ar][koff];    ah[1]=*(const bf16x8*)&Ah[ar+16][koff];
        al[0]=*(const bf16x8*)&Al[ar][koff];    al[1]=*(const bf16x8*)&Al[ar+16][koff];
        bh[0]=*(const bf16x8*)&Bh[br][koff];    bh[1]=*(const bf16x8*)&Bh[br+16][koff];
        bl[0]=*(const bf16x8*)&Bl[br][koff];    bl[1]=*(const bf16x8*)&Bl[br+16][koff];
        #pragma unroll
        for (int fm=0; fm<2; ++fm)
        #pragma unroll
        for (int fn=0; fn<2; ++fn){
            acc[fm][fn] = __builtin_amdgcn_mfma_f32_16x16x32_bf16(ah[fm], bh[fn], acc[fm][fn],0,0,0);
            acc[fm][fn] = __builtin_amdgcn_mfma_f32_16x16x32_bf16(ah[fm], bl[fn], acc[fm][fn],0,0,0);
            acc[fm][fn] = __builtin_amdgcn_mfma_f32_16x16x32_bf16(al[fm], bh[fn], acc[fm][fn],0,0,0);
        }
    }
    #pragma unroll
    for (int fm=0; fm<2; ++fm)
    #pragma unroll
    for (int fn=0; fn<2; ++fn){
        #pragma unroll
        for (int r=0; r<4; ++r){
            int m = bm*64 + wm*32 + fm*16 + ((l>>4)<<2) + r;
            int n = bn*64 + wn*32 + fn*16 + (l&15);
            float bias = 0.f;
            if (bias1) bias += bias1[m];
            if (bias2) bias += bias2[m];
            C[(size_t)m*N + n] = acc[fm][fn][r] + bias;
        }
    }
}

// ---------------- K1b: LSTM pointwise ----------------------------------
__global__ __launch_bounds__(256) void lstm_pointwise(
    const float* __restrict__ gates, const float* __restrict__ c_in,
    float* __restrict__ h_out, float* __restrict__ c_out)
{
    int t = blockIdx.x*256 + threadIdx.x;
    int b = t >> 9, hh = t & 511;
    float gi = gates[(size_t)(0*512+hh)*128 + b];
    float gf = gates[(size_t)(1*512+hh)*128 + b];
    float gg = gates[(size_t)(2*512+hh)*128 + b];
    float go = gates[(size_t)(3*512+hh)*128 + b];
    float i = sigmoidf_(gi), f = sigmoidf_(gf), g = tanhf(gg), o = sigmoidf_(go);
    float cn = f*c_in[t] + i*g;
    float hn = o*tanhf(cn);
    h_out[t] = hn;  c_out[t] = cn;
}

// ---------------- K3: main fused GEMM + tanh*V reduce ------------------
// BM=128 rows/block (one batch b per block: 4 blocks per b), full N=512.
// 8 waves, wave grid 2M x 4N: each wave 64 rows x 128 cols.
// A: staged ONCE to LDS (fp32->bf16, XOR-swizzled 16B slots). B: W1bf is
// L2-resident (512KB) -> register loads, no LDS, no barriers in K-loop.
__global__ __launch_bounds__(512,2) void attn_main(
    const float* __restrict__ enc, const bf16* __restrict__ W1bf,
    const float* __restrict__ w2h, const float* __restrict__ Vv,
    float* __restrict__ a_out)
{
    __shared__ bf16 Alds[128*512];   // 128 KiB, [row][slot^((row&7))] 16B slots
    __shared__ float w2h_s[512];
    __shared__ float V_s[512];
    __shared__ float red[128][4];
    int tid = threadIdx.x;
    int w = tid>>6, l = tid&63;
    int wm = w>>2, wn = w&3;
    int m0 = blockIdx.x * 128;
    int bidx = blockIdx.x >> 2;      // batch index (512 rows per batch)
    w2h_s[tid] = w2h[(size_t)tid*128 + bidx];
    V_s[tid]   = Vv[tid];

    // ---- stage A once: 128 rows x 512 k, fp32 -> bf16, swizzled ----
    #pragma unroll
    for (int it = 0; it < 16; ++it){
        int c   = it*512 + tid;          // 16B-chunk id, 64 chunks/row
        int row = c >> 6, s16 = c & 63;
        const f32x4* gp = (const f32x4*)&enc[(size_t)(m0+row)*512 + s16*8];
        f32x4 v0 = gp[0], v1 = gp[1];
        bf16x8 hv;
        #pragma unroll
        for (int j=0;j<4;++j){ hv[j]=(bf16)v0[j]; hv[4+j]=(bf16)v1[j]; }
        int slot = s16 ^ (row & 7);
        *(bf16x8*)((char*)Alds + row*1024 + slot*16) = hv;
    }
    __syncthreads();

    const int lr = l & 15, lk = l >> 4;
    const bf16* Bbase = W1bf + (size_t)(wn*128 + lr)*512 + lk*8;
    f32x4 acc[4][8] = {};

    bf16x8 bA[8], bB[8];
    #pragma unroll
    for (int fn=0; fn<8; ++fn) bA[fn] = *(const bf16x8*)(Bbase + (size_t)fn*16*512);

    #pragma unroll
    for (int kp = 0; kp < 8; ++kp){
        int ki0 = 2*kp, ki1 = 2*kp+1;
        // prefetch odd
        #pragma unroll
        for (int fn=0; fn<8; ++fn) bB[fn] = *(const bf16x8*)(Bbase + (size_t)fn*16*512 + ki1*32);
        // even compute
        {
            bf16x8 af[4];
            #pragma unroll
            for (int fm=0; fm<4; ++fm){
                int row = wm*64 + fm*16 + lr;
                int slot = (ki0*4 + lk) ^ (row & 7);
                af[fm] = *(const bf16x8*)((const char*)Alds + row*1024 + slot*16);
            }
            #pragma unroll
            for (int fm=0; fm<4; ++fm)
            #pragma unroll
            for (int fn=0; fn<8; ++fn)
                acc[fm][fn] = __builtin_amdgcn_mfma_f32_16x16x32_bf16(af[fm], bA[fn], acc[fm][fn],0,0,0);
        }
        // prefetch next even
        if (kp < 7){
            #pragma unroll
            for (int fn=0; fn<8; ++fn) bA[fn] = *(const bf16x8*)(Bbase + (size_t)fn*16*512 + (ki0+2)*32);
        }
        // odd compute
        {
            bf16x8 af[4];
            #pragma unroll
            for (int fm=0; fm<4; ++fm){
                int row = wm*64 + fm*16 + lr;
                int slot = (ki1*4 + lk) ^ (row & 7);
                af[fm] = *(const bf16x8*)((const char*)Alds + row*1024 + slot*16);
            }
            #pragma unroll
            for (int fm=0; fm<4; ++fm)
            #pragma unroll
            for (int fn=0; fn<8; ++fn)
                acc[fm][fn] = __builtin_amdgcn_mfma_f32_16x16x32_bf16(af[fm], bB[fn], acc[fm][fn],0,0,0);
        }
    }

    // ---- epilogue: per row, sum_o tanh(C+w2h[o])*V[o] ----
    #pragma unroll
    for (int fm=0; fm<4; ++fm){
        float asum[4] = {0.f,0.f,0.f,0.f};
        #pragma unroll
        for (int fn=0; fn<8; ++fn){
            int o = wn*128 + fn*16 + lr;
            float wv = w2h_s[o], vv = V_s[o];
            #pragma unroll
            for (int r=0;r<4;++r)
                asum[r] += tanhf(acc[fm][fn][r] + wv) * vv;
        }
        #pragma unroll
        for (int off=1; off<16; off<<=1){
            #pragma unroll
            for (int r=0;r<4;++r) asum[r] += __shfl_xor(asum[r], off, 64);
        }
        if (lr == 0){
            #pragma unroll
            for (int r=0;r<4;++r) red[wm*64 + fm*16 + lk*4 + r][wn] = asum[r];
        }
    }
    __syncthreads();
    if (tid < 128){
        float a = red[tid][0] + red[tid][1] + red[tid][2] + red[tid][3];
        a_out[m0 + tid] = 10.0f * tanhf(a);
    }
}

// ---------------- K4: masked softmax over S=512 per row ----------------
__global__ __launch_bounds__(512) void softmax_k(
    const float* __restrict__ a10, const float* __restrict__ mask,
    float* __restrict__ out)
{
    int b = blockIdx.x, tid = threadIdx.x;
    __shared__ float sred[8];
    float v = a10[(size_t)b*512 + tid] + logf(mask[(size_t)b*512 + tid]);
    float m = v;
    #pragma unroll
    for (int off=1; off<64; off<<=1) m = fmaxf(m, __shfl_xor(m, off, 64));
    if ((tid&63)==0) sred[tid>>6] = m;
    __syncthreads();
    float mt = sred[0];
    #pragma unroll
    for (int i=1;i<8;++i) mt = fmaxf(mt, sred[i]);
    float e = expf(v - mt);
    float s = e;
    #pragma unroll
    for (int off=1; off<64; off<<=1) s += __shfl_xor(s, off, 64);
    __syncthreads();
    if ((tid&63)==0) sred[tid>>6] = s;
    __syncthreads();
    float st = 0.f;
    #pragma unroll
    for (int i=0;i<8;++i) st += sred[i];
    out[(size_t)b*512 + tid] = e / st;
}

extern "C" void kernel_launch(void* const* d_in, const int* in_sizes, int n_in,
                              void* d_out, int out_size, void* d_ws, size_t ws_size,
                              hipStream_t stream)
{
    const float* x    = (const float*)d_in[0];
    const float* h    = (const float*)d_in[1];
    const float* c    = (const float*)d_in[2];
    const float* enc  = (const float*)d_in[3];
    const float* mask = (const float*)d_in[4];
    const float* W1   = (const float*)d_in[5];
    const float* W2   = (const float*)d_in[6];
    const float* b2   = (const float*)d_in[7];
    const float* V    = (const float*)d_in[8];
    const float* Wih  = (const float*)d_in[9];
    const float* Whh  = (const float*)d_in[10];
    const float* bih  = (const float*)d_in[11];
    const float* bhh  = (const float*)d_in[12];

    float* out_policy = (float*)d_out;
    float* out_h = out_policy + MS;
    float* out_c = out_policy + 2*MS;

    float* ws_f  = (float*)d_ws;
    float* gates = ws_f;                 // 262144 f32
    float* w2h   = ws_f + 262144;        //  65536 f32  [o][b]
    float* a10   = ws_f + 327680;        //  65536 f32
    bf16*  W1bf  = (bf16*)(ws_f + 393216); // 262144 bf16

    cvt_w1<<<256, 256, 0, stream>>>(W1, W1bf);
    gemm_split<<<dim3(32,2), 256, 0, stream>>>(Wih, Whh, x, h, bih, bhh, gates, 128, 2);
    lstm_pointwise<<<256, 256, 0, stream>>>(gates, c, out_h, out_c);
    gemm_split<<<dim3(8,2), 256, 0, stream>>>(W2, nullptr, out_h, nullptr, b2, nullptr, w2h, 128, 1);
    attn_main<<<512, 512, 0, stream>>>(enc, W1bf, w2h, V, a10);
    softmax_k<<<128, 512, 0, stream>>>(a10, mask, out_policy);
}

// Round 4
// 116.800 us; speedup vs baseline: 1.5413x; 1.4300x over previous
//
#include <hip/hip_runtime.h>
#include <hip/hip_bf16.h>
#include <math.h>

typedef __bf16 bf16;
typedef __bf16 bf16x4 __attribute__((ext_vector_type(4)));
typedef __bf16 bf16x8 __attribute__((ext_vector_type(8)));
typedef float  f32x4  __attribute__((ext_vector_type(4)));

#define HD 512
#define NB 128
#define NS 512
#define MS (NB*NS)   // 65536

__device__ __forceinline__ float sigmoidf_(float x){ return 1.0f/(1.0f+expf(-x)); }

// fast tanh: 1 v_exp + 1 v_rcp + a few VALU; |err| ~1e-6 (<< bf16 noise)
__device__ __forceinline__ float fast_tanh(float x){
    float ax = fabsf(x);
    float e  = __expf(-2.0f*ax);            // (0,1], no overflow
    float t  = (1.0f - e) * __builtin_amdgcn_rcpf(1.0f + e);
    return copysignf(t, x);
}

// ---- K0: shuffle W1 (512x512 fp32, row-major [o][h]) into MFMA B-fragment
// order, bf16.  Fragment (fn,ki): lane l holds W1[fn*16+(l&15)][ki*32+(l>>4)*8+j],
// stored at W1s[((fn*16+ki)*64 + l)*8 + j]  -> each B-frag load is one
// coalesced 64-lane x 16B instruction.
__global__ __launch_bounds__(256) void cvt_w1_frag(const float* __restrict__ W1, bf16* __restrict__ W1s){
    int wid = blockIdx.x*4 + (threadIdx.x>>6);   // 512 waves: fn=wid>>4, ki=wid&15
    int l   = threadIdx.x & 63;
    int fn = wid >> 4, ki = wid & 15;
    int row = fn*16 + (l & 15);
    int kk  = ki*32 + (l >> 4)*8;
    const f32x4* gp = (const f32x4*)&W1[(size_t)row*512 + kk];
    f32x4 v0 = gp[0], v1 = gp[1];
    bf16x8 hv;
    #pragma unroll
    for (int j=0;j<4;++j){ hv[j]=(bf16)v0[j]; hv[4+j]=(bf16)v1[j]; }
    *(bf16x8*)&W1s[(size_t)((fn*16 + ki)*64 + l)*8] = hv;
}

// ---------------- K1/K2: small GEMM, 3-term bf16 split (fp32-grade) ----
__global__ __launch_bounds__(256) void gemm_split(
    const float* __restrict__ A1, const float* __restrict__ A2,
    const float* __restrict__ B1, const float* __restrict__ B2,
    const float* __restrict__ bias1, const float* __restrict__ bias2,
    float* __restrict__ C, int N, int Ksegs)
{
    __shared__ bf16 Ah[64][32], Al[64][32], Bh[64][32], Bl[64][32];
    int tid = threadIdx.x;
    int bm = blockIdx.x, bn = blockIdx.y;
    int w = tid>>6, l = tid&63;
    int wm = w>>1, wn = w&1;
    f32x4 acc[2][2] = {};
    int KT = Ksegs*512;
    for (int k0 = 0; k0 < KT; k0 += 32){
        const float* Ap = (k0 < 512) ? A1 : A2;
        const float* Bp = (k0 < 512) ? B1 : B2;
        int kk = k0 & 511;
        __syncthreads();
        #pragma unroll
        for (int q = 0; q < 2; ++q){
            int id  = q*256 + tid;
            int row = id >> 3, c4 = (id & 7)*4;
            f32x4 va = *(const f32x4*)&Ap[(size_t)(bm*64+row)*512 + kk + c4];
            f32x4 vb = *(const f32x4*)&Bp[(size_t)(bn*64+row)*512 + kk + c4];
            bf16x4 vah, val_, vbh, vbl;
            #pragma unroll
            for (int j=0;j<4;++j){
                bf16 ha = (bf16)va[j]; vah[j]=ha; val_[j]=(bf16)(va[j]-(float)ha);
                bf16 hb = (bf16)vb[j]; vbh[j]=hb; vbl[j]=(bf16)(vb[j]-(float)hb);
            }
            *(bf16x4*)&Ah[row][c4] = vah;  *(bf16x4*)&Al[row][c4] = val_;
            *(bf16x4*)&Bh[row][c4] = vbh;  *(bf16x4*)&Bl[row][c4] = vbl;
        }
        __syncthreads();
        int koff = (l>>4)*8;
        int ar = wm*32 + (l&15);
        int br = wn*32 + (l&15);
        bf16x8 ah[2], al[2], bh[2], bl[2];
        ah[0]=*(const bf16x8*)&Ah[ar][koff];    ah[1]=*(const bf16x8*)&Ah[ar+16][koff];
        al[0]=*(const bf16x8*)&Al[ar][koff];    al[1]=*(const bf16x8*)&Al[ar+16][koff];
        bh[0]=*(const bf16x8*)&Bh[br][koff];    bh[1]=*(const bf16x8*)&Bh[br+16][koff];
        bl[0]=*(const bf16x8*)&Bl[br][koff];    bl[1]=*(const bf16x8*)&Bl[br+16][koff];
        #pragma unroll
        for (int fm=0; fm<2; ++fm)
        #pragma unroll
        for (int fn=0; fn<2; ++fn){
            acc[fm][fn] = __builtin_amdgcn_mfma_f32_16x16x32_bf16(ah[fm], bh[fn], acc[fm][fn],0,0,0);
            acc[fm][fn] = __builtin_amdgcn_mfma_f32_16x16x32_bf16(ah[fm], bl[fn], acc[fm][fn],0,0,0);
            acc[fm][fn] = __builtin_amdgcn_mfma_f32_16x16x32_bf16(al[fm], bh[fn], acc[fm][fn],0,0,0);
        }
    }
    #pragma unroll
    for (int fm=0; fm<2; ++fm)
    #pragma unroll
    for (int fn=0; fn<2; ++fn){
        #pragma unroll
        for (int r=0; r<4; ++r){
            int m = bm*64 + wm*32 + fm*16 + ((l>>4)<<2) + r;
            int n = bn*64 + wn*32 + fn*16 + (l&15);
            float bias = 0.f;
            if (bias1) bias += bias1[m];
            if (bias2) bias += bias2[m];
            C[(size_t)m*N + n] = acc[fm][fn][r] + bias;
        }
    }
}

// ---------------- K1b: LSTM pointwise ----------------------------------
__global__ __launch_bounds__(256) void lstm_pointwise(
    const float* __restrict__ gates, const float* __restrict__ c_in,
    float* __restrict__ h_out, float* __restrict__ c_out)
{
    int t = blockIdx.x*256 + threadIdx.x;
    int b = t >> 9, hh = t & 511;
    float gi = gates[(size_t)(0*512+hh)*128 + b];
    float gf = gates[(size_t)(1*512+hh)*128 + b];
    float gg = gates[(size_t)(2*512+hh)*128 + b];
    float go = gates[(size_t)(3*512+hh)*128 + b];
    float i = sigmoidf_(gi), f = sigmoidf_(gf), g = tanhf(gg), o = sigmoidf_(go);
    float cn = f*c_in[t] + i*g;
    float hn = o*tanhf(cn);
    h_out[t] = hn;  c_out[t] = cn;
}

// ---------------- K3: main fused GEMM + tanh*V reduce ------------------
// BM=128 rows/block, full N=512.  8 waves (2M x 4N), wave = 64r x 128c.
// A: staged once to LDS (fp32->bf16, XOR swizzle).  B: fragment-ordered
// W1s from L2, fully-coalesced register loads, zero K-loop barriers.
__global__ __launch_bounds__(512,2) void attn_main(
    const float* __restrict__ enc, const bf16* __restrict__ W1s,
    const float* __restrict__ w2h, const float* __restrict__ Vv,
    float* __restrict__ a_out)
{
    __shared__ bf16 Alds[128*512];   // 128 KiB, [row][slot^(row&7)] 16B slots
    __shared__ float w2h_s[512];
    __shared__ float V_s[512];
    __shared__ float red[128][4];
    int tid = threadIdx.x;
    int w = tid>>6, l = tid&63;
    int wm = w>>2, wn = w&3;
    int m0 = blockIdx.x * 128;
    int bidx = blockIdx.x >> 2;      // batch index (4 blocks per batch row-group)
    w2h_s[tid] = w2h[(size_t)tid*128 + bidx];
    V_s[tid]   = Vv[tid];

    const int lr = l & 15, lk = l >> 4;
    // fragment-ordered B base for this wave/lane: frag (wn*8+fnl, ki) at
    // base + fnl*8192 + ki*512 elements
    const bf16* Bbase = W1s + (size_t)wn*65536 + (size_t)l*8;

    // prefetch first B parity BEFORE the staging barrier (L2 overlaps HBM)
    bf16x8 bA[8], bB[8];
    #pragma unroll
    for (int fn=0; fn<8; ++fn) bA[fn] = *(const bf16x8*)(Bbase + fn*8192);

    // ---- stage A once: 128 rows x 512 k, fp32 -> bf16, swizzled ----
    #pragma unroll
    for (int it = 0; it < 16; ++it){
        int c   = it*512 + tid;          // 16B-chunk id, 64 chunks/row
        int row = c >> 6, s16 = c & 63;
        const f32x4* gp = (const f32x4*)&enc[(size_t)(m0+row)*512 + s16*8];
        f32x4 v0 = gp[0], v1 = gp[1];
        bf16x8 hv;
        #pragma unroll
        for (int j=0;j<4;++j){ hv[j]=(bf16)v0[j]; hv[4+j]=(bf16)v1[j]; }
        int slot = s16 ^ (row & 7);
        *(bf16x8*)((char*)Alds + row*1024 + slot*16) = hv;
    }
    __syncthreads();

    f32x4 acc[4][8] = {};

    #pragma unroll
    for (int kp = 0; kp < 8; ++kp){
        int ki0 = 2*kp, ki1 = 2*kp+1;
        // prefetch odd
        #pragma unroll
        for (int fn=0; fn<8; ++fn) bB[fn] = *(const bf16x8*)(Bbase + fn*8192 + ki1*512);
        // even compute
        {
            bf16x8 af[4];
            #pragma unroll
            for (int fm=0; fm<4; ++fm){
                int row = wm*64 + fm*16 + lr;
                int slot = (ki0*4 + lk) ^ (row & 7);
                af[fm] = *(const bf16x8*)((const char*)Alds + row*1024 + slot*16);
            }
            #pragma unroll
            for (int fm=0; fm<4; ++fm)
            #pragma unroll
            for (int fn=0; fn<8; ++fn)
                acc[fm][fn] = __builtin_amdgcn_mfma_f32_16x16x32_bf16(af[fm], bA[fn], acc[fm][fn],0,0,0);
        }
        // prefetch next even
        if (kp < 7){
            #pragma unroll
            for (int fn=0; fn<8; ++fn) bA[fn] = *(const bf16x8*)(Bbase + fn*8192 + (ki0+2)*512);
        }
        // odd compute
        {
            bf16x8 af[4];
            #pragma unroll
            for (int fm=0; fm<4; ++fm){
                int row = wm*64 + fm*16 + lr;
                int slot = (ki1*4 + lk) ^ (row & 7);
                af[fm] = *(const bf16x8*)((const char*)Alds + row*1024 + slot*16);
            }
            #pragma unroll
            for (int fm=0; fm<4; ++fm)
            #pragma unroll
            for (int fn=0; fn<8; ++fn)
                acc[fm][fn] = __builtin_amdgcn_mfma_f32_16x16x32_bf16(af[fm], bB[fn], acc[fm][fn],0,0,0);
        }
    }

    // ---- epilogue: per row, sum_o tanh(C+w2h[o])*V[o] ----
    #pragma unroll
    for (int fm=0; fm<4; ++fm){
        float asum[4] = {0.f,0.f,0.f,0.f};
        #pragma unroll
        for (int fn=0; fn<8; ++fn){
            int o = wn*128 + fn*16 + lr;
            float wv = w2h_s[o], vv = V_s[o];
            #pragma unroll
            for (int r=0;r<4;++r)
                asum[r] += fast_tanh(acc[fm][fn][r] + wv) * vv;
        }
        #pragma unroll
        for (int off=1; off<16; off<<=1){
            #pragma unroll
            for (int r=0;r<4;++r) asum[r] += __shfl_xor(asum[r], off, 64);
        }
        if (lr == 0){
            #pragma unroll
            for (int r=0;r<4;++r) red[wm*64 + fm*16 + lk*4 + r][wn] = asum[r];
        }
    }
    __syncthreads();
    if (tid < 128){
        float a = red[tid][0] + red[tid][1] + red[tid][2] + red[tid][3];
        a_out[m0 + tid] = 10.0f * fast_tanh(a);
    }
}

// ---------------- K4: masked softmax over S=512 per row ----------------
__global__ __launch_bounds__(512) void softmax_k(
    const float* __restrict__ a10, const float* __restrict__ mask,
    float* __restrict__ out)
{
    int b = blockIdx.x, tid = threadIdx.x;
    __shared__ float sred[8];
    float v = a10[(size_t)b*512 + tid] + logf(mask[(size_t)b*512 + tid]);
    float m = v;
    #pragma unroll
    for (int off=1; off<64; off<<=1) m = fmaxf(m, __shfl_xor(m, off, 64));
    if ((tid&63)==0) sred[tid>>6] = m;
    __syncthreads();
    float mt = sred[0];
    #pragma unroll
    for (int i=1;i<8;++i) mt = fmaxf(mt, sred[i]);
    float e = expf(v - mt);
    float s = e;
    #pragma unroll
    for (int off=1; off<64; off<<=1) s += __shfl_xor(s, off, 64);
    __syncthreads();
    if ((tid&63)==0) sred[tid>>6] = s;
    __syncthreads();
    float st = 0.f;
    #pragma unroll
    for (int i=0;i<8;++i) st += sred[i];
    out[(size_t)b*512 + tid] = e / st;
}

extern "C" void kernel_launch(void* const* d_in, const int* in_sizes, int n_in,
                              void* d_out, int out_size, void* d_ws, size_t ws_size,
                              hipStream_t stream)
{
    const float* x    = (const float*)d_in[0];
    const float* h    = (const float*)d_in[1];
    const float* c    = (const float*)d_in[2];
    const float* enc  = (const float*)d_in[3];
    const float* mask = (const float*)d_in[4];
    const float* W1   = (const float*)d_in[5];
    const float* W2   = (const float*)d_in[6];
    const float* b2   = (const float*)d_in[7];
    const float* V    = (const float*)d_in[8];
    const float* Wih  = (const float*)d_in[9];
    const float* Whh  = (const float*)d_in[10];
    const float* bih  = (const float*)d_in[11];
    const float* bhh  = (const float*)d_in[12];

    float* out_policy = (float*)d_out;
    float* out_h = out_policy + MS;
    float* out_c = out_policy + 2*MS;

    float* ws_f  = (float*)d_ws;
    float* gates = ws_f;                 // 262144 f32
    float* w2h   = ws_f + 262144;        //  65536 f32  [o][b]
    float* a10   = ws_f + 327680;        //  65536 f32
    bf16*  W1s   = (bf16*)(ws_f + 393216); // 262144 bf16 (fragment-ordered)

    cvt_w1_frag<<<128, 256, 0, stream>>>(W1, W1s);
    gemm_split<<<dim3(32,2), 256, 0, stream>>>(Wih, Whh, x, h, bih, bhh, gates, 128, 2);
    lstm_pointwise<<<256, 256, 0, stream>>>(gates, c, out_h, out_c);
    gemm_split<<<dim3(8,2), 256, 0, stream>>>(W2, nullptr, out_h, nullptr, b2, nullptr, w2h, 128, 1);
    attn_main<<<512, 512, 0, stream>>>(enc, W1s, w2h, V, a10);
    softmax_k<<<128, 512, 0, stream>>>(a10, mask, out_policy);
}

// Round 5
// 112.070 us; speedup vs baseline: 1.6064x; 1.0422x over previous
//
#include <hip/hip_runtime.h>
#include <hip/hip_bf16.h>
#include <math.h>

typedef __bf16 bf16;
typedef __bf16 bf16x4 __attribute__((ext_vector_type(4)));
typedef __bf16 bf16x8 __attribute__((ext_vector_type(8)));
typedef float  f32x4  __attribute__((ext_vector_type(4)));

#define HD 512
#define NB 128
#define NS 512
#define MS (NB*NS)   // 65536

__device__ __forceinline__ float sigmoidf_(float x){ return 1.0f/(1.0f+expf(-x)); }

// fast tanh: 1 v_exp + 1 v_rcp + a few VALU; |err| ~1e-6 (<< bf16 noise)
__device__ __forceinline__ float fast_tanh(float x){
    float ax = fabsf(x);
    float e  = __expf(-2.0f*ax);            // (0,1], no overflow
    float t  = (1.0f - e) * __builtin_amdgcn_rcpf(1.0f + e);
    return copysignf(t, x);
}

// ---- K0: shuffle W1 (512x512 fp32, row-major [o][h]) into MFMA B-fragment
// order, bf16.  Fragment (fn,ki): lane l holds W1[fn*16+(l&15)][ki*32+(l>>4)*8+j],
// stored at W1s[((fn*16+ki)*64 + l)*8 + j].
__global__ __launch_bounds__(256) void cvt_w1_frag(const float* __restrict__ W1, bf16* __restrict__ W1s){
    int wid = blockIdx.x*4 + (threadIdx.x>>6);   // 512 waves: fn=wid>>4, ki=wid&15
    int l   = threadIdx.x & 63;
    int fn = wid >> 4, ki = wid & 15;
    int row = fn*16 + (l & 15);
    int kk  = ki*32 + (l >> 4)*8;
    const f32x4* gp = (const f32x4*)&W1[(size_t)row*512 + kk];
    f32x4 v0 = gp[0], v1 = gp[1];
    bf16x8 hv;
    #pragma unroll
    for (int j=0;j<4;++j){ hv[j]=(bf16)v0[j]; hv[4+j]=(bf16)v1[j]; }
    *(bf16x8*)&W1s[(size_t)((fn*16 + ki)*64 + l)*8] = hv;
}

// ---------------- K1/K2: small GEMM, 3-term bf16 split (fp32-grade) ----
__global__ __launch_bounds__(256) void gemm_split(
    const float* __restrict__ A1, const float* __restrict__ A2,
    const float* __restrict__ B1, const float* __restrict__ B2,
    const float* __restrict__ bias1, const float* __restrict__ bias2,
    float* __restrict__ C, int N, int Ksegs)
{
    __shared__ bf16 Ah[64][32], Al[64][32], Bh[64][32], Bl[64][32];
    int tid = threadIdx.x;
    int bm = blockIdx.x, bn = blockIdx.y;
    int w = tid>>6, l = tid&63;
    int wm = w>>1, wn = w&1;
    f32x4 acc[2][2] = {};
    int KT = Ksegs*512;
    for (int k0 = 0; k0 < KT; k0 += 32){
        const float* Ap = (k0 < 512) ? A1 : A2;
        const float* Bp = (k0 < 512) ? B1 : B2;
        int kk = k0 & 511;
        __syncthreads();
        #pragma unroll
        for (int q = 0; q < 2; ++q){
            int id  = q*256 + tid;
            int row = id >> 3, c4 = (id & 7)*4;
            f32x4 va = *(const f32x4*)&Ap[(size_t)(bm*64+row)*512 + kk + c4];
            f32x4 vb = *(const f32x4*)&Bp[(size_t)(bn*64+row)*512 + kk + c4];
            bf16x4 vah, val_, vbh, vbl;
            #pragma unroll
            for (int j=0;j<4;++j){
                bf16 ha = (bf16)va[j]; vah[j]=ha; val_[j]=(bf16)(va[j]-(float)ha);
                bf16 hb = (bf16)vb[j]; vbh[j]=hb; vbl[j]=(bf16)(vb[j]-(float)hb);
            }
            *(bf16x4*)&Ah[row][c4] = vah;  *(bf16x4*)&Al[row][c4] = val_;
            *(bf16x4*)&Bh[row][c4] = vbh;  *(bf16x4*)&Bl[row][c4] = vbl;
        }
        __syncthreads();
        int koff = (l>>4)*8;
        int ar = wm*32 + (l&15);
        int br = wn*32 + (l&15);
        bf16x8 ah[2], al[2], bh[2], bl[2];
        ah[0]=*(const bf16x8*)&Ah[ar][koff];    ah[1]=*(const bf16x8*)&Ah[ar+16][koff];
        al[0]=*(const bf16x8*)&Al[ar][koff];    al[1]=*(const bf16x8*)&Al[ar+16][koff];
        bh[0]=*(const bf16x8*)&Bh[br][koff];    bh[1]=*(const bf16x8*)&Bh[br+16][koff];
        bl[0]=*(const bf16x8*)&Bl[br][koff];    bl[1]=*(const bf16x8*)&Bl[br+16][koff];
        #pragma unroll
        for (int fm=0; fm<2; ++fm)
        #pragma unroll
        for (int fn=0; fn<2; ++fn){
            acc[fm][fn] = __builtin_amdgcn_mfma_f32_16x16x32_bf16(ah[fm], bh[fn], acc[fm][fn],0,0,0);
            acc[fm][fn] = __builtin_amdgcn_mfma_f32_16x16x32_bf16(ah[fm], bl[fn], acc[fm][fn],0,0,0);
            acc[fm][fn] = __builtin_amdgcn_mfma_f32_16x16x32_bf16(al[fm], bh[fn], acc[fm][fn],0,0,0);
        }
    }
    #pragma unroll
    for (int fm=0; fm<2; ++fm)
    #pragma unroll
    for (int fn=0; fn<2; ++fn){
        #pragma unroll
        for (int r=0; r<4; ++r){
            int m = bm*64 + wm*32 + fm*16 + ((l>>4)<<2) + r;
            int n = bn*64 + wn*32 + fn*16 + (l&15);
            float bias = 0.f;
            if (bias1) bias += bias1[m];
            if (bias2) bias += bias2[m];
            C[(size_t)m*N + n] = acc[fm][fn][r] + bias;
        }
    }
}

// ---------------- K1b: LSTM pointwise ----------------------------------
__global__ __launch_bounds__(256) void lstm_pointwise(
    const float* __restrict__ gates, const float* __restrict__ c_in,
    float* __restrict__ h_out, float* __restrict__ c_out)
{
    int t = blockIdx.x*256 + threadIdx.x;
    int b = t >> 9, hh = t & 511;
    float gi = gates[(size_t)(0*512+hh)*128 + b];
    float gf = gates[(size_t)(1*512+hh)*128 + b];
    float gg = gates[(size_t)(2*512+hh)*128 + b];
    float go = gates[(size_t)(3*512+hh)*128 + b];
    float i = sigmoidf_(gi), f = sigmoidf_(gf), g = tanhf(gg), o = sigmoidf_(go);
    float cn = f*c_in[t] + i*g;
    float hn = o*tanhf(cn);
    h_out[t] = hn;  c_out[t] = cn;
}

// ---------------- K3: main fused GEMM + tanh*V reduce ------------------
// BM=64 rows/block, 1024 blocks, full N=512.  8 waves 1M x 8N: each wave
// 64 rows x 64 cols (acc 64/lane -> 2 blocks/CU co-resident; one block's
// compute hides the other's HBM staging).  A: full-K LDS tile (64 KB,
// fp32->bf16, slot^(row&15) swizzle -> conflict-free 16-row reads).
// B: fragment-ordered W1s from L2, coalesced register loads, no barriers.
__global__ __launch_bounds__(512,4) void attn_main(
    const float* __restrict__ enc, const bf16* __restrict__ W1s,
    const float* __restrict__ w2h, const float* __restrict__ Vv,
    float* __restrict__ a_out)
{
    __shared__ bf16 Alds[64*512];    // 64 KiB, [row][slot^(row&15)] 16B slots
    __shared__ float w2h_s[512];
    __shared__ float V_s[512];
    __shared__ float red[64][8];
    int tid = threadIdx.x;
    int w = tid>>6, l = tid&63;
    int m0 = blockIdx.x * 64;
    int bidx = blockIdx.x >> 3;      // batch index (8 blocks per batch)
    w2h_s[tid] = w2h[(size_t)tid*128 + bidx];
    V_s[tid]   = Vv[tid];

    const int lr = l & 15, lk = l >> 4;
    // wave w covers cols [w*64, w*64+64): global fn = w*4 + fnl
    const bf16* Bbase = W1s + (size_t)w*32768 + (size_t)l*8;

    // prefetch first B parity BEFORE staging (L2 overlaps HBM)
    bf16x8 bA[4], bB[4];
    #pragma unroll
    for (int fn=0; fn<4; ++fn) bA[fn] = *(const bf16x8*)(Bbase + fn*8192);

    // ---- stage A once: 64 rows x 512 k, fp32 -> bf16, swizzled ----
    #pragma unroll
    for (int it = 0; it < 8; ++it){
        int c   = it*512 + tid;          // 16B-slot id: 64 slots/row
        int row = c >> 6, s = c & 63;
        const f32x4* gp = (const f32x4*)&enc[(size_t)(m0+row)*512 + s*8];
        f32x4 v0 = gp[0], v1 = gp[1];
        bf16x8 hv;
        #pragma unroll
        for (int j=0;j<4;++j){ hv[j]=(bf16)v0[j]; hv[4+j]=(bf16)v1[j]; }
        int slot = s ^ (row & 15);
        *(bf16x8*)((char*)Alds + row*1024 + slot*16) = hv;
    }
    __syncthreads();

    f32x4 acc[4][4] = {};

    #pragma unroll
    for (int kp = 0; kp < 8; ++kp){
        int ki0 = 2*kp, ki1 = 2*kp+1;
        // prefetch odd
        #pragma unroll
        for (int fn=0; fn<4; ++fn) bB[fn] = *(const bf16x8*)(Bbase + fn*8192 + ki1*512);
        // even compute
        {
            bf16x8 af[4];
            #pragma unroll
            for (int fm=0; fm<4; ++fm){
                int row = fm*16 + lr;
                int slot = (ki0*4 + lk) ^ (row & 15);
                af[fm] = *(const bf16x8*)((const char*)Alds + row*1024 + slot*16);
            }
            #pragma unroll
            for (int fm=0; fm<4; ++fm)
            #pragma unroll
            for (int fn=0; fn<4; ++fn)
                acc[fm][fn] = __builtin_amdgcn_mfma_f32_16x16x32_bf16(af[fm], bA[fn], acc[fm][fn],0,0,0);
        }
        // prefetch next even
        if (kp < 7){
            #pragma unroll
            for (int fn=0; fn<4; ++fn) bA[fn] = *(const bf16x8*)(Bbase + fn*8192 + (ki0+2)*512);
        }
        // odd compute
        {
            bf16x8 af[4];
            #pragma unroll
            for (int fm=0; fm<4; ++fm){
                int row = fm*16 + lr;
                int slot = (ki1*4 + lk) ^ (row & 15);
                af[fm] = *(const bf16x8*)((const char*)Alds + row*1024 + slot*16);
            }
            #pragma unroll
            for (int fm=0; fm<4; ++fm)
            #pragma unroll
            for (int fn=0; fn<4; ++fn)
                acc[fm][fn] = __builtin_amdgcn_mfma_f32_16x16x32_bf16(af[fm], bB[fn], acc[fm][fn],0,0,0);
        }
    }

    // ---- epilogue: per row, sum_o tanh(C+w2h[o])*V[o] ----
    #pragma unroll
    for (int fm=0; fm<4; ++fm){
        float asum[4] = {0.f,0.f,0.f,0.f};
        #pragma unroll
        for (int fn=0; fn<4; ++fn){
            int o = w*64 + fn*16 + lr;
            float wv = w2h_s[o], vv = V_s[o];
            #pragma unroll
            for (int r=0;r<4;++r)
                asum[r] += fast_tanh(acc[fm][fn][r] + wv) * vv;
        }
        #pragma unroll
        for (int off=1; off<16; off<<=1){
            #pragma unroll
            for (int r=0;r<4;++r) asum[r] += __shfl_xor(asum[r], off, 64);
        }
        if (lr == 0){
            #pragma unroll
            for (int r=0;r<4;++r) red[fm*16 + lk*4 + r][w] = asum[r];
        }
    }
    __syncthreads();
    if (tid < 64){
        float a = 0.f;
        #pragma unroll
        for (int q=0;q<8;++q) a += red[tid][q];
        a_out[m0 + tid] = 10.0f * fast_tanh(a);
    }
}

// ---------------- K4: masked softmax over S=512 per row ----------------
__global__ __launch_bounds__(512) void softmax_k(
    const float* __restrict__ a10, const float* __restrict__ mask,
    float* __restrict__ out)
{
    int b = blockIdx.x, tid = threadIdx.x;
    __shared__ float sred[8];
    float v = a10[(size_t)b*512 + tid] + logf(mask[(size_t)b*512 + tid]);
    float m = v;
    #pragma unroll
    for (int off=1; off<64; off<<=1) m = fmaxf(m, __shfl_xor(m, off, 64));
    if ((tid&63)==0) sred[tid>>6] = m;
    __syncthreads();
    float mt = sred[0];
    #pragma unroll
    for (int i=1;i<8;++i) mt = fmaxf(mt, sred[i]);
    float e = expf(v - mt);
    float s = e;
    #pragma unroll
    for (int off=1; off<64; off<<=1) s += __shfl_xor(s, off, 64);
    __syncthreads();
    if ((tid&63)==0) sred[tid>>6] = s;
    __syncthreads();
    float st = 0.f;
    #pragma unroll
    for (int i=0;i<8;++i) st += sred[i];
    out[(size_t)b*512 + tid] = e / st;
}

extern "C" void kernel_launch(void* const* d_in, const int* in_sizes, int n_in,
                              void* d_out, int out_size, void* d_ws, size_t ws_size,
                              hipStream_t stream)
{
    const float* x    = (const float*)d_in[0];
    const float* h    = (const float*)d_in[1];
    const float* c    = (const float*)d_in[2];
    const float* enc  = (const float*)d_in[3];
    const float* mask = (const float*)d_in[4];
    const float* W1   = (const float*)d_in[5];
    const float* W2   = (const float*)d_in[6];
    const float* b2   = (const float*)d_in[7];
    const float* V    = (const float*)d_in[8];
    const float* Wih  = (const float*)d_in[9];
    const float* Whh  = (const float*)d_in[10];
    const float* bih  = (const float*)d_in[11];
    const float* bhh  = (const float*)d_in[12];

    float* out_policy = (float*)d_out;
    float* out_h = out_policy + MS;
    float* out_c = out_policy + 2*MS;

    float* ws_f  = (float*)d_ws;
    float* gates = ws_f;                 // 262144 f32
    float* w2h   = ws_f + 262144;        //  65536 f32  [o][b]
    float* a10   = ws_f + 327680;        //  65536 f32
    bf16*  W1s   = (bf16*)(ws_f + 393216); // 262144 bf16 (fragment-ordered)

    cvt_w1_frag<<<128, 256, 0, stream>>>(W1, W1s);
    gemm_split<<<dim3(32,2), 256, 0, stream>>>(Wih, Whh, x, h, bih, bhh, gates, 128, 2);
    lstm_pointwise<<<256, 256, 0, stream>>>(gates, c, out_h, out_c);
    gemm_split<<<dim3(8,2), 256, 0, stream>>>(W2, nullptr, out_h, nullptr, b2, nullptr, w2h, 128, 1);
    attn_main<<<1024, 512, 0, stream>>>(enc, W1s, w2h, V, a10);
    softmax_k<<<128, 512, 0, stream>>>(a10, mask, out_policy);
}

// Round 6
// 96.237 us; speedup vs baseline: 1.8706x; 1.1645x over previous
//
#include <hip/hip_runtime.h>
#include <hip/hip_bf16.h>
#include <math.h>

typedef __bf16 bf16;
typedef __bf16 bf16x4 __attribute__((ext_vector_type(4)));
typedef __bf16 bf16x8 __attribute__((ext_vector_type(8)));
typedef float  f32x4  __attribute__((ext_vector_type(4)));

#define HD 512
#define NB 128
#define NS 512
#define MS (NB*NS)   // 65536

__device__ __forceinline__ float sigmoidf_(float x){ return 1.0f/(1.0f+expf(-x)); }

// fast tanh: 1 v_exp + 1 v_rcp + a few VALU; |err| ~1e-6 (<< bf16 noise)
__device__ __forceinline__ float fast_tanh(float x){
    float ax = fabsf(x);
    float e  = __expf(-2.0f*ax);
    float t  = (1.0f - e) * __builtin_amdgcn_rcpf(1.0f + e);
    return copysignf(t, x);
}

// ---- K0: W1 (512x512 fp32 [o][h]) -> bf16 MFMA B-fragment order.
// Frag id F = (w*16 + ki)*4 + fnl  (w=wave 0..7, ki=K-parity 0..15, fnl=0..3).
// Lane l of frag F holds W1[(w*4+fnl)*16 + (l&15)][ki*32 + (l>>4)*8 + j],
// at W1s[F*512 + l*8 + j].  A wave's 4 frags for one ki are contiguous 4KB.
__global__ __launch_bounds__(256) void cvt_w1_frag(const float* __restrict__ W1, bf16* __restrict__ W1s){
    int F = blockIdx.x*4 + (threadIdx.x>>6);
    int l = threadIdx.x & 63;
    int fnl = F & 3, ki = (F>>2) & 15, w = F>>6;
    int row = (w*4 + fnl)*16 + (l & 15);
    int kk  = ki*32 + (l >> 4)*8;
    const f32x4* gp = (const f32x4*)&W1[(size_t)row*512 + kk];
    f32x4 v0 = gp[0], v1 = gp[1];
    bf16x8 hv;
    #pragma unroll
    for (int j=0;j<4;++j){ hv[j]=(bf16)v0[j]; hv[4+j]=(bf16)v1[j]; }
    *(bf16x8*)&W1s[(size_t)F*512 + (size_t)l*8] = hv;
}

// ---- K1/K2: small GEMM, 3-term bf16 split, SPLIT-K (grid.z), transposed
// output partials: Cz[n*ldct + m], Cz = C + z*N*ldct.  Bias added in z==0.
__global__ __launch_bounds__(256) void gemm_split(
    const float* __restrict__ A1, const float* __restrict__ A2,
    const float* __restrict__ B1, const float* __restrict__ B2,
    const float* __restrict__ bias1, const float* __restrict__ bias2,
    float* __restrict__ C, int N, int ksize, int ldct)
{
    __shared__ bf16 Ah[64][32], Al[64][32], Bh[64][32], Bl[64][32];
    int tid = threadIdx.x;
    int bm = blockIdx.x, bn = blockIdx.y, ks = blockIdx.z;
    int kfrom = ks*ksize, kend = kfrom + ksize;
    float* Cz = C + (size_t)ks * N * ldct;
    int w = tid>>6, l = tid&63;
    int wm = w>>1, wn = w&1;
    f32x4 acc[2][2] = {};
    for (int k0 = kfrom; k0 < kend; k0 += 32){
        const float* Ap = (k0 < 512) ? A1 : A2;
        const float* Bp = (k0 < 512) ? B1 : B2;
        int kk = k0 & 511;
        __syncthreads();
        #pragma unroll
        for (int q = 0; q < 2; ++q){
            int id  = q*256 + tid;
            int row = id >> 3, c4 = (id & 7)*4;
            f32x4 va = *(const f32x4*)&Ap[(size_t)(bm*64+row)*512 + kk + c4];
            f32x4 vb = *(const f32x4*)&Bp[(size_t)(bn*64+row)*512 + kk + c4];
            bf16x4 vah, val_, vbh, vbl;
            #pragma unroll
            for (int j=0;j<4;++j){
                bf16 ha = (bf16)va[j]; vah[j]=ha; val_[j]=(bf16)(va[j]-(float)ha);
                bf16 hb = (bf16)vb[j]; vbh[j]=hb; vbl[j]=(bf16)(vb[j]-(float)hb);
            }
            *(bf16x4*)&Ah[row][c4] = vah;  *(bf16x4*)&Al[row][c4] = val_;
            *(bf16x4*)&Bh[row][c4] = vbh;  *(bf16x4*)&Bl[row][c4] = vbl;
        }
        __syncthreads();
        int koff = (l>>4)*8;
        int ar = wm*32 + (l&15);
        int br = wn*32 + (l&15);
        bf16x8 ah[2], al[2], bh[2], bl[2];
        ah[0]=*(const bf16x8*)&Ah[ar][koff];    ah[1]=*(const bf16x8*)&Ah[ar+16][koff];
        al[0]=*(const bf16x8*)&Al[ar][koff];    al[1]=*(const bf16x8*)&Al[ar+16][koff];
        bh[0]=*(const bf16x8*)&Bh[br][koff];    bh[1]=*(const bf16x8*)&Bh[br+16][koff];
        bl[0]=*(const bf16x8*)&Bl[br][koff];    bl[1]=*(const bf16x8*)&Bl[br+16][koff];
        #pragma unroll
        for (int fm=0; fm<2; ++fm)
        #pragma unroll
        for (int fn=0; fn<2; ++fn){
            acc[fm][fn] = __builtin_amdgcn_mfma_f32_16x16x32_bf16(ah[fm], bh[fn], acc[fm][fn],0,0,0);
            acc[fm][fn] = __builtin_amdgcn_mfma_f32_16x16x32_bf16(ah[fm], bl[fn], acc[fm][fn],0,0,0);
            acc[fm][fn] = __builtin_amdgcn_mfma_f32_16x16x32_bf16(al[fm], bh[fn], acc[fm][fn],0,0,0);
        }
    }
    #pragma unroll
    for (int fm=0; fm<2; ++fm)
    #pragma unroll
    for (int fn=0; fn<2; ++fn){
        #pragma unroll
        for (int r=0; r<4; ++r){
            int m = bm*64 + wm*32 + fm*16 + ((l>>4)<<2) + r;
            int n = bn*64 + wn*32 + fn*16 + (l&15);
            float v = acc[fm][fn][r];
            if (ks == 0){
                if (bias1) v += bias1[m];
                if (bias2) v += bias2[m];
            }
            Cz[(size_t)n*ldct + m] = v;
        }
    }
}

// ---- K1b: LSTM pointwise (sums 4 split-K partials, transposed layout) ----
__global__ __launch_bounds__(256) void lstm_pointwise(
    const float* __restrict__ gatesT, const float* __restrict__ c_in,
    float* __restrict__ h_out, float* __restrict__ c_out)
{
    int t = blockIdx.x*256 + threadIdx.x;
    int b = t >> 9, hh = t & 511;
    const float* gp = gatesT + (size_t)b*2048 + hh;
    float gi=0.f, gf=0.f, gg=0.f, go=0.f;
    #pragma unroll
    for (int ks=0; ks<4; ++ks){
        const float* p = gp + (size_t)ks*262144;
        gi += p[0]; gf += p[512]; gg += p[1024]; go += p[1536];
    }
    float i = sigmoidf_(gi), f = sigmoidf_(gf), g = tanhf(gg), o = sigmoidf_(go);
    float cn = f*c_in[t] + i*g;
    float hn = o*tanhf(cn);
    h_out[t] = hn;  c_out[t] = cn;
}

// ---------------- K3 helpers ----------------
__device__ __forceinline__ void pref_b(const bf16* base, bf16x8* dst){
    #pragma unroll
    for (int fnl=0; fnl<4; ++fnl) dst[fnl] = *(const bf16x8*)(base + fnl*512);
}

__device__ __forceinline__ void comp_par(const bf16* buf, int kil, int lr, int lk,
                                         const bf16x8* b, f32x4 (&acc)[4][4]){
    bf16x8 af[4];
    #pragma unroll
    for (int fm=0; fm<4; ++fm){
        int row  = fm*16 + lr;
        int slot = (kil*4 + lk) ^ (row & 15);
        af[fm] = *(const bf16x8*)((const char*)buf + row*256 + slot*16);
    }
    #pragma unroll
    for (int fm=0; fm<4; ++fm)
    #pragma unroll
    for (int fn=0; fn<4; ++fn)
        acc[fm][fn] = __builtin_amdgcn_mfma_f32_16x16x32_bf16(af[fm], b[fn], acc[fm][fn],0,0,0);
}

// producer: stage one K-chunk (64 rows x 128 k fp32 -> bf16, swizzled 16B slots)
__device__ __forceinline__ void produce_chunk(const float* ep, int kc, bf16* buf, int l){
    #pragma unroll
    for (int j=0; j<16; ++j){
        int c = l + j*64;                 // slot id: r = c>>4 (0..63), s = c&15
        int r = c >> 4, s = c & 15;
        const float* p = ep + (size_t)r*512 + kc*128 + s*8;
        f32x4 v0 = *(const f32x4*)p;
        f32x4 v1 = *(const f32x4*)(p+4);
        bf16x8 hv;
        #pragma unroll
        for (int jj=0;jj<4;++jj){ hv[jj]=(bf16)v0[jj]; hv[4+jj]=(bf16)v1[jj]; }
        *(bf16x8*)((char*)buf + r*256 + ((s ^ (r & 15))*16)) = hv;
    }
}

// ---- K3: fused GEMM + tanh*V reduce, producer/consumer wave split.
// 576 threads: waves 0..7 consume (64r x 64c each, as r5), wave 8 produces
// A-chunks (K-chunk=128, double-buffered LDS).  Consumer vmcnt counts only
// its own L2 B-prefetches (per-wave counter) -> HBM staging never gates MFMA.
__global__ __launch_bounds__(576,3) void attn_main(
    const float* __restrict__ enc, const bf16* __restrict__ W1s,
    const float* __restrict__ w2hp, const float* __restrict__ Vv,
    float* __restrict__ a_out)
{
    __shared__ bf16 Alds[2][64*128];   // 2 x 16 KiB
    __shared__ float w2h_s[512];
    __shared__ float V_s[512];
    __shared__ float red[64][8];
    const int tid = threadIdx.x, w = tid>>6, l = tid&63;
    const int lr = l & 15, lk = l >> 4;
    const int m0 = blockIdx.x * 64;
    const int bidx = blockIdx.x >> 3;
    if (tid < 512){
        w2h_s[tid] = w2hp[(size_t)bidx*512 + tid] + w2hp[(size_t)65536 + bidx*512 + tid];
        V_s[tid]   = Vv[tid];
    }

    if (w == 8){
        // ---------------- producer wave ----------------
        const float* ep = enc + (size_t)m0*512;
        produce_chunk(ep, 0, Alds[0], l);
        __syncthreads();                      // B1: chunk0 ready
        produce_chunk(ep, 1, Alds[1], l);
        __syncthreads();                      // B2
        produce_chunk(ep, 2, Alds[0], l);
        __syncthreads();                      // B3
        produce_chunk(ep, 3, Alds[1], l);
        __syncthreads();                      // B4
        __syncthreads();                      // B5
    } else {
        // ---------------- consumer waves ----------------
        const bf16* Bbase = W1s + (size_t)w*32768 + (size_t)l*8;
        bf16x8 bA[4], bB[4];
        pref_b(Bbase, bA);                    // ki=0
        f32x4 acc[4][4] = {};
        __syncthreads();                      // B1
        #pragma unroll
        for (int kc=0; kc<4; ++kc){
            const bf16* bufc = Alds[kc&1];
            pref_b(Bbase + (kc*4+1)*2048, bB);
            comp_par(bufc, 0, lr, lk, bA, acc);
            pref_b(Bbase + (kc*4+2)*2048, bA);
            comp_par(bufc, 1, lr, lk, bB, acc);
            pref_b(Bbase + (kc*4+3)*2048, bB);
            comp_par(bufc, 2, lr, lk, bA, acc);
            if (kc < 3) pref_b(Bbase + (kc*4+4)*2048, bA);
            comp_par(bufc, 3, lr, lk, bB, acc);
            __syncthreads();                  // B2..B5
        }
        // epilogue: per row, sum_o tanh(C + w2h[o]) * V[o]
        #pragma unroll
        for (int fm=0; fm<4; ++fm){
            float asum[4] = {0.f,0.f,0.f,0.f};
            #pragma unroll
            for (int fn=0; fn<4; ++fn){
                int o = w*64 + fn*16 + lr;
                float wv = w2h_s[o], vv = V_s[o];
                #pragma unroll
                for (int r=0;r<4;++r)
                    asum[r] += fast_tanh(acc[fm][fn][r] + wv) * vv;
            }
            #pragma unroll
            for (int off=1; off<16; off<<=1){
                #pragma unroll
                for (int r=0;r<4;++r) asum[r] += __shfl_xor(asum[r], off, 64);
            }
            if (lr == 0){
                #pragma unroll
                for (int r=0;r<4;++r) red[fm*16 + lk*4 + r][w] = asum[r];
            }
        }
    }
    __syncthreads();                          // B6
    if (tid < 64){
        float a = 0.f;
        #pragma unroll
        for (int q=0;q<8;++q) a += red[tid][q];
        a_out[m0 + tid] = 10.0f * fast_tanh(a);
    }
}

// ---- K4: masked softmax over S=512 per row ----
__global__ __launch_bounds__(512) void softmax_k(
    const float* __restrict__ a10, const float* __restrict__ mask,
    float* __restrict__ out)
{
    int b = blockIdx.x, tid = threadIdx.x;
    __shared__ float sred[8];
    float v = a10[(size_t)b*512 + tid] + logf(mask[(size_t)b*512 + tid]);
    float m = v;
    #pragma unroll
    for (int off=1; off<64; off<<=1) m = fmaxf(m, __shfl_xor(m, off, 64));
    if ((tid&63)==0) sred[tid>>6] = m;
    __syncthreads();
    float mt = sred[0];
    #pragma unroll
    for (int i=1;i<8;++i) mt = fmaxf(mt, sred[i]);
    float e = expf(v - mt);
    float s = e;
    #pragma unroll
    for (int off=1; off<64; off<<=1) s += __shfl_xor(s, off, 64);
    __syncthreads();
    if ((tid&63)==0) sred[tid>>6] = s;
    __syncthreads();
    float st = 0.f;
    #pragma unroll
    for (int i=0;i<8;++i) st += sred[i];
    out[(size_t)b*512 + tid] = e / st;
}

extern "C" void kernel_launch(void* const* d_in, const int* in_sizes, int n_in,
                              void* d_out, int out_size, void* d_ws, size_t ws_size,
                              hipStream_t stream)
{
    const float* x    = (const float*)d_in[0];
    const float* h    = (const float*)d_in[1];
    const float* c    = (const float*)d_in[2];
    const float* enc  = (const float*)d_in[3];
    const float* mask = (const float*)d_in[4];
    const float* W1   = (const float*)d_in[5];
    const float* W2   = (const float*)d_in[6];
    const float* b2   = (const float*)d_in[7];
    const float* V    = (const float*)d_in[8];
    const float* Wih  = (const float*)d_in[9];
    const float* Whh  = (const float*)d_in[10];
    const float* bih  = (const float*)d_in[11];
    const float* bhh  = (const float*)d_in[12];

    float* out_policy = (float*)d_out;
    float* out_h = out_policy + MS;
    float* out_c = out_policy + 2*MS;

    float* ws_f   = (float*)d_ws;
    float* gatesT = ws_f;                    // 4 x 262144 f32 (split-K partials, [b][j])
    float* w2hp   = ws_f + 1048576;          // 2 x  65536 f32 (split-K partials, [b][o])
    float* a10    = ws_f + 1179648;          //      65536 f32
    bf16*  W1s    = (bf16*)(ws_f + 1245184); //     262144 bf16 (fragment-ordered)

    cvt_w1_frag<<<128, 256, 0, stream>>>(W1, W1s);
    // gates: M=2048(j), N=128(b), K=1024 split 4x256 -> gatesT partials
    gemm_split<<<dim3(32,2,4), 256, 0, stream>>>(Wih, Whh, x, h, bih, bhh, gatesT, 128, 256, 2048);
    lstm_pointwise<<<256, 256, 0, stream>>>(gatesT, c, out_h, out_c);
    // w2h: M=512(o), N=128(b), K=512 split 2x256 -> w2hp partials
    gemm_split<<<dim3(8,2,2), 256, 0, stream>>>(W2, nullptr, out_h, nullptr, b2, nullptr, w2hp, 128, 256, 512);
    attn_main<<<1024, 576, 0, stream>>>(enc, W1s, w2hp, V, a10);
    softmax_k<<<128, 512, 0, stream>>>(a10, mask, out_policy);
}